// Round 21
// baseline (102.341 us; speedup 1.0000x reference)
//
#include <hip/hip_runtime.h>
#include <math.h>

#define NUM_LEVELS 5
#define NUM_CLASSES 80
#define TOPK 1000
#define CAND_CAP 4096
#define NBINS 2048
#define NREP 16
#define FLOORV 0.5f
#define BIN_W (0.5f / 2048.0f)
#define INV_BIN_W (2048.0f / 0.5f)

typedef float f32x4 __attribute__((ext_vector_type(4)));

struct LevelParams {
    const float* cls[NUM_LEVELS];
    const float* box[NUM_LEVELS];
    const float* pss[NUM_LEVELS];
};

// Step-rounded f32 sigmoid, numpy scalar semantics (bit-matches golden; R6-R20 pass).
__device__ __forceinline__ float np_sigmoid_f32(float x) {
    float e32 = (float)exp(-(double)x);
    float d = __fadd_rn(1.0f, e32);
    return __fdiv_rn(1.0f, d);
}

__device__ __forceinline__ float max4v(f32x4 a) {
    return fmaxf(fmaxf(a.x, a.y), fmaxf(a.z, a.w));
}

// Zero histR (16*5*2048 u32) + count[5].
__global__ __launch_bounds__(256) void k_zero(unsigned* histR, int* count) {
    int i = blockIdx.x * 256 + threadIdx.x;   // 640*256 == 163840 exact
    histR[i] = 0u;
    if (i < NUM_LEVELS) count[i] = 0;
}

// Balanced: 1705 blocks x exactly 4 units (1024 float4), nontemporal cls loads.
// Chunk(8)-max -> bf16-trunc ushort store (7MB) + floor-0.5 test + 2048-bin LDS
// hist, NREP-replica flush. Byte-identical to R20 (passed).
__global__ __launch_bounds__(256) void k_hist(LevelParams P, unsigned* histR, unsigned short* mh) {
    __shared__ unsigned lh[NBINS];
    for (int i = threadIdx.x; i < NBINS; i += 256) lh[i] = 0;
    __syncthreads();

    const int bid = blockIdx.x;
    int lev, lb, roff;
    if (bid < 1280)      { lev = 0; lb = bid;        roff = 0; }
    else if (bid < 1600) { lev = 1; lb = bid - 1280; roff = 262144; }
    else if (bid < 1680) { lev = 2; lb = bid - 1600; roff = 327680; }
    else if (bid < 1700) { lev = 3; lb = bid - 1680; roff = 344064; }
    else                 { lev = 4; lb = bid - 1700; roff = 348160; }
    const int start = lb * 4;                 // 4 units of 1024 float4, exact

    const f32x4* __restrict__ cls4 = (const f32x4*)P.cls[lev];
    const float* __restrict__ pss_l = P.pss[lev];
    unsigned short* __restrict__ mh_l = mh + (size_t)roff * 10;   // 10 chunks/row
    const int t = (int)threadIdx.x;
    const bool even = (t & 1) == 0;

    const f32x4* pc = cls4 + start * 1024 + t;
    f32x4 c0 = __builtin_nontemporal_load(pc);
    f32x4 c1 = __builtin_nontemporal_load(pc + 256);
    f32x4 c2 = __builtin_nontemporal_load(pc + 512);
    f32x4 c3 = __builtin_nontemporal_load(pc + 768);

    int u = start;
#pragma unroll
    for (int it = 0; it < 4; ++it) {
        const bool more = (it < 3);
        const f32x4* pn = cls4 + (more ? (u + 1) : u) * 1024 + t;
        f32x4 n0 = __builtin_nontemporal_load(pn);
        f32x4 n1 = __builtin_nontemporal_load(pn + 256);
        f32x4 n2 = __builtin_nontemporal_load(pn + 512);
        f32x4 n3 = __builtin_nontemporal_load(pn + 768);

        const int i4b = u * 1024 + t;
#pragma unroll
        for (int s = 0; s < 4; ++s) {
            f32x4 c = (s == 0) ? c0 : (s == 1) ? c1 : (s == 2) ? c2 : c3;
            int i4 = i4b + s * 256;
            float m = max4v(c);
            float m2 = fmaxf(m, __shfl_xor(m, 1));
            if (even) {
                int chunk = i4 >> 1;
                mh_l[chunk] = (unsigned short)(__float_as_uint(m2) >> 16);  // bf16 trunc
                float p = pss_l[chunk / 10];
                float E = __expf(-m2);
                float A = 1.0f + __expf(-p);
                float sc = __frcp_rn((1.0f + E) * A);
                if (sc >= FLOORV) {
                    int b = (int)((sc - FLOORV) * INV_BIN_W);
                    if (b > NBINS - 1) b = NBINS - 1;
                    atomicAdd(&lh[b], 1u);
                }
            }
        }
        u = u + 1; c0 = n0; c1 = n1; c2 = n2; c3 = n3;
    }

    __syncthreads();
    unsigned* h = histR + (size_t)(bid & (NREP - 1)) * (NUM_LEVELS * NBINS) + lev * NBINS;
    for (int i = threadIdx.x; i < NBINS; i += 256) {
        unsigned v = lh[i];
        if (v) atomicAdd(&h[i], v);
    }
}

// Merged: sum NREP replicas (coalesced per iteration) + crossing scan + count zero.
__global__ __launch_bounds__(256) void k_cutoff(const unsigned* histR, float* cutL, int* count) {
    __shared__ unsigned sh[NBINS];
    __shared__ unsigned ps[256];
    const int lev = blockIdx.x;
    const int t = (int)threadIdx.x;
    for (int i = t; i < NBINS; i += 256) {
        unsigned s = 0;
#pragma unroll
        for (int rp = 0; rp < NREP; ++rp)
            s += histR[(size_t)rp * (NUM_LEVELS * NBINS) + lev * NBINS + i];
        sh[i] = s;
    }
    __syncthreads();
    unsigned seg = 0;
#pragma unroll
    for (int j = 0; j < 8; ++j) seg += sh[t * 8 + j];
    ps[t] = seg;
    __syncthreads();
    if (t == 0) {
        long cum = 0;
        int sgi = 255;
        for (; sgi >= 0; --sgi) {
            if (cum + ps[sgi] >= TOPK) break;
            cum += ps[sgi];
        }
        int b = 0;
        if (sgi >= 0) {
            for (int j = sgi * 8 + 7; j >= sgi * 8; --j) {
                cum += sh[j];
                if (cum >= TOPK) { b = j; break; }
            }
        }
        int sel = (b <= 0) ? 0 : (b - 1);   // one margin bin below crossing
        cutL[lev] = FLOORV + (float)sel * BIN_W;
        count[lev] = 0;
    }
}

// Scan mh (7MB ushort, coalesced) vs per-row c-space cutoff; bf16-trunc slack on
// chunk skip; element test exact f32 vs ct. Byte-identical to R20 (passed).
__global__ __launch_bounds__(1024) void k_compact(LevelParams P, const float* cutL,
                                                  const unsigned short* mh, int* count, int* cand) {
    const int bid = blockIdx.x;
    int lev, bstart, roff;
    if (bid < 2560)      { lev = 0; bstart = 0;    roff = 0; }
    else if (bid < 3200) { lev = 1; bstart = 2560; roff = 262144; }
    else if (bid < 3360) { lev = 2; bstart = 3200; roff = 327680; }
    else if (bid < 3400) { lev = 3; bstart = 3360; roff = 344064; }
    else                 { lev = 4; bstart = 3400; roff = 348160; }

    const int cid = (bid - bstart) * 1024 + (int)threadIdx.x;   // level-local chunk
    const float* __restrict__ pss_l = P.pss[lev];
    float mv = __uint_as_float((unsigned)mh[(size_t)roff * 10 + cid] << 16);
    float p = pss_l[cid / 10];
    float A = 1.0f + __expf(-p);
    const float thr = cutL[lev] - 1e-4f;
    float gg = __frcp_rn(thr * A) - 1.0f;            // e^-c <= gg <=> s >= thr
    float ct = (gg > 0.0f) ? (-__logf(gg) - 1e-2f) : 1e30f;
    bool pass = mv >= ct - 0.05f;                    // bf16-trunc slack
    if (__syncthreads_count(pass) == 0) return;

    __shared__ int lcount;
    __shared__ int lbase;
    __shared__ int lbuf[2048];
    if (threadIdx.x == 0) lcount = 0;
    __syncthreads();

    if (pass) {
        const float* __restrict__ cls = P.cls[lev];
        const int el = cid * 8;
        float4 c0 = *(const float4*)(cls + el);
        float4 c1 = *(const float4*)(cls + el + 4);
        float cs[8] = {c0.x, c0.y, c0.z, c0.w, c1.x, c1.y, c1.z, c1.w};
#pragma unroll
        for (int j = 0; j < 8; ++j) {
            if (cs[j] >= ct) {
                int li = atomicAdd(&lcount, 1);
                if (li < 2048) lbuf[li] = el + j;
            }
        }
    }
    __syncthreads();
    if (threadIdx.x == 0) lbase = atomicAdd(&count[lev], lcount);  // ONE global atomic/block
    __syncthreads();
    const int m = lcount < 2048 ? lcount : 2048;
    const int base = lbase;
    for (int i = threadIdx.x; i < m; i += 1024) {
        int pos = base + i;
        if (pos < CAND_CAP) cand[lev * CAND_CAP + pos] = lbuf[i];
    }
}

__global__ __launch_bounds__(1024) void k_final(LevelParams P, const int* cand, const int* count,
                                                const int* wptr, const int* hptr, float* out) {
    // Packed u64 keys: (f32 score bits << 32) | (0xFFFFFFFF - idx).
    // Descending sort == descending score, ties -> ascending index.
    __shared__ unsigned long long sk[CAND_CAP];
    const int lev = blockIdx.x;
    int n = count[lev];
    if (n > CAND_CAP) n = CAND_CAP;
    const int t = (int)threadIdx.x;

    const float* __restrict__ cls = P.cls[lev];
    const float* __restrict__ pss = P.pss[lev];
    const float* __restrict__ box = P.box[lev];

    const float w = (float)wptr[0], h = (float)hptr[0];
    const float invw = 1.0f / w, invh = 1.0f / h;

    if (n <= 2048) {
        // ---- register+shuffle bitonic, V=2048, thread t owns elements {t, t+1024} ----
        unsigned long long r0, r1;
        {
            int i0 = t, i1 = t + 1024;
            if (i0 < n) {
                int idx = cand[lev * CAND_CAP + i0];
                float s = __fmul_rn(np_sigmoid_f32(cls[idx]), np_sigmoid_f32(pss[idx / NUM_CLASSES]));
                r0 = ((unsigned long long)(unsigned)__float_as_int(s) << 32)
                     | (unsigned long long)(0xFFFFFFFFu - (unsigned)idx);
            } else r0 = 0ull;
            if (i1 < n) {
                int idx = cand[lev * CAND_CAP + i1];
                float s = __fmul_rn(np_sigmoid_f32(cls[idx]), np_sigmoid_f32(pss[idx / NUM_CLASSES]));
                r1 = ((unsigned long long)(unsigned)__float_as_int(s) << 32)
                     | (unsigned long long)(0xFFFFFFFFu - (unsigned)idx);
            } else r1 = 0ull;
        }
        for (int k = 2; k <= 2048; k <<= 1) {
            if (k == 2048) {
                // j=1024: thread-local pair (t, t+1024); low index = t, dir = desc
                unsigned long long lo = (r0 > r1) ? r0 : r1;
                unsigned long long hi = (r0 > r1) ? r1 : r0;
                r0 = lo; r1 = hi;
            }
            const bool dir0 = ((t & k) == 0);                 // element t
            const bool dir1 = (((t + 1024) & k) == 0);        // element t+1024
            for (int j = (k == 2048 ? 512 : (k >> 1)); j >= 1; j >>= 1) {
                unsigned long long p0, p1;
                if (j >= 64) {
                    sk[t] = r0; sk[t + 1024] = r1;
                    __syncthreads();
                    p0 = sk[t ^ j]; p1 = sk[(t ^ j) + 1024];
                    __syncthreads();
                } else {
                    p0 = __shfl_xor(r0, j);
                    p1 = __shfl_xor(r1, j);
                }
                const bool low = ((t & j) == 0);              // same for t and t+1024 (j<=512)
                r0 = ((dir0 == low) ? ((r0 > p0) ? r0 : p0) : ((r0 > p0) ? p0 : r0));
                r1 = ((dir1 == low) ? ((r1 > p1) ? r1 : p1) : ((r1 > p1) ? p1 : r1));
            }
        }
        // thread t holds sorted element t in r0; only ranks < TOPK matter.
        if (t < TOPK) {
            unsigned long long v = r0;
            float s = __int_as_float((int)(unsigned)(v >> 32));
            int idx = (int)(0xFFFFFFFFu - (unsigned)(v & 0xFFFFFFFFull));
            bool keep = (t < n) && (s > 0.05f);
            int row = lev * TOPK + t;
            float b0 = 0.f, b1 = 0.f, b2 = 0.f, b3 = 0.f;
            if (keep) {
                int a = idx / NUM_CLASSES;
                b0 = fminf(fmaxf(box[a * 4 + 0] * invw, 0.f), 1.f);
                b1 = fminf(fmaxf(box[a * 4 + 1] * invh, 0.f), 1.f);
                b2 = fminf(fmaxf(box[a * 4 + 2] * invw, 0.f), 1.f);
                b3 = fminf(fmaxf(box[a * 4 + 3] * invh, 0.f), 1.f);
            }
            out[row * 4 + 0] = b0;
            out[row * 4 + 1] = b1;
            out[row * 4 + 2] = b2;
            out[row * 4 + 3] = b3;
            out[NUM_LEVELS * TOPK * 4 + row] = keep ? s : 0.0f;
            out[NUM_LEVELS * TOPK * 5 + row] = keep ? (float)(idx % NUM_CLASSES) : -1.0f;
        }
        return;
    }

    // ---- fallback (n > 2048): verbatim R20 LDS bitonic ----
    int size = 1024;
    while (size < n) size <<= 1;
    for (int i = t; i < size; i += 1024) {
        if (i < n) {
            int idx = cand[lev * CAND_CAP + i];
            float a32 = np_sigmoid_f32(cls[idx]);
            float b32 = np_sigmoid_f32(pss[idx / NUM_CLASSES]);
            float s = __fmul_rn(a32, b32);
            sk[i] = ((unsigned long long)(unsigned)__float_as_int(s) << 32)
                    | (unsigned long long)(0xFFFFFFFFu - (unsigned)idx);
        } else {
            sk[i] = 0ull;
        }
    }
    __syncthreads();
    for (int k = 2; k <= size; k <<= 1) {
        for (int j = k >> 1; j > 0; j >>= 1) {
            for (int q = t; q < (size >> 1); q += 1024) {
                int i = ((q & ~(j - 1)) << 1) | (q & (j - 1));
                int ix = i | j;
                unsigned long long a = sk[i], b = sk[ix];
                bool dirDesc = ((i & k) == 0);
                if ((a > b) != dirDesc) { sk[i] = b; sk[ix] = a; }
            }
            __syncthreads();
        }
    }
    for (int r = t; r < TOPK; r += 1024) {
        unsigned long long v = sk[r];
        float s = __int_as_float((int)(unsigned)(v >> 32));
        int idx = (int)(0xFFFFFFFFu - (unsigned)(v & 0xFFFFFFFFull));
        bool keep = (r < n) && (s > 0.05f);
        int row = lev * TOPK + r;
        float b0 = 0.f, b1 = 0.f, b2 = 0.f, b3 = 0.f;
        if (keep) {
            int a = idx / NUM_CLASSES;
            b0 = fminf(fmaxf(box[a * 4 + 0] * invw, 0.f), 1.f);
            b1 = fminf(fmaxf(box[a * 4 + 1] * invh, 0.f), 1.f);
            b2 = fminf(fmaxf(box[a * 4 + 2] * invw, 0.f), 1.f);
            b3 = fminf(fmaxf(box[a * 4 + 3] * invh, 0.f), 1.f);
        }
        out[row * 4 + 0] = b0;
        out[row * 4 + 1] = b1;
        out[row * 4 + 2] = b2;
        out[row * 4 + 3] = b3;
        out[NUM_LEVELS * TOPK * 4 + row] = keep ? s : 0.0f;
        out[NUM_LEVELS * TOPK * 5 + row] = keep ? (float)(idx % NUM_CLASSES) : -1.0f;
    }
}

extern "C" void kernel_launch(void* const* d_in, const int* in_sizes, int n_in,
                              void* d_out, int out_size, void* d_ws, size_t ws_size,
                              hipStream_t stream) {
    LevelParams P;
    for (int i = 0; i < NUM_LEVELS; ++i) {
        P.cls[i] = (const float*)d_in[3 * i + 0];
        P.box[i] = (const float*)d_in[3 * i + 1];
        P.pss[i] = (const float*)d_in[3 * i + 2];
    }
    const int* wp = (const int*)d_in[15];
    const int* hp = (const int*)d_in[16];

    unsigned char* ws = (unsigned char*)d_ws;
    unsigned* histR = (unsigned*)ws;                 // 16*5*2048*4 = 655,360
    float* cutL = (float*)(ws + 655360);             // 20 B
    int* count = (int*)(ws + 655380);                // 20 B
    unsigned short* mh = (unsigned short*)(ws + 655424);  // 3,491,840*2 -> ends 7,639,104
    int* cand = (int*)(ws + 7639104);                // 81,920

    k_zero<<<640, 256, 0, stream>>>(histR, count);
    k_hist<<<1705, 256, 0, stream>>>(P, histR, mh);
    k_cutoff<<<NUM_LEVELS, 256, 0, stream>>>(histR, cutL, count);
    k_compact<<<3410, 1024, 0, stream>>>(P, cutL, mh, count, cand);
    k_final<<<NUM_LEVELS, 1024, 0, stream>>>(P, cand, count, wp, hp, (float*)d_out);
}

// Round 22
// 93.650 us; speedup vs baseline: 1.0928x; 1.0928x over previous
//
#include <hip/hip_runtime.h>
#include <math.h>

#define NUM_LEVELS 5
#define NUM_CLASSES 80
#define TOPK 1000
#define CAND_CAP 4096
#define NBINS 2048
#define NREP 16
#define FLOORV 0.5f
#define BIN_W (0.5f / 2048.0f)
#define INV_BIN_W (2048.0f / 0.5f)

typedef float f32x4 __attribute__((ext_vector_type(4)));

struct LevelParams {
    const float* cls[NUM_LEVELS];
    const float* box[NUM_LEVELS];
    const float* pss[NUM_LEVELS];
};

// Step-rounded f32 sigmoid, numpy scalar semantics (bit-matches golden; R6-R21 pass).
__device__ __forceinline__ float np_sigmoid_f32(float x) {
    float e32 = (float)exp(-(double)x);
    float d = __fadd_rn(1.0f, e32);
    return __fdiv_rn(1.0f, d);
}

__device__ __forceinline__ float max4v(f32x4 a) {
    return fmaxf(fmaxf(a.x, a.y), fmaxf(a.z, a.w));
}

// Zero histR (16*5*2048 u32).
__global__ __launch_bounds__(256) void k_zero(unsigned* histR) {
    histR[blockIdx.x * 256 + threadIdx.x] = 0u;   // 640*256 == 163840 exact
}

// Balanced: 1705 blocks x exactly 4 units (1024 float4), nontemporal cls loads.
// Chunk(8)-max -> bf16-trunc ushort store (7MB) + floor-0.5 test (f32, A inline
// from pss) + 2048-bin LDS hist, NREP-replica flush.
__global__ __launch_bounds__(256) void k_hist(LevelParams P, unsigned* histR, unsigned short* mh) {
    __shared__ unsigned lh[NBINS];
    for (int i = threadIdx.x; i < NBINS; i += 256) lh[i] = 0;
    __syncthreads();

    const int bid = blockIdx.x;
    int lev, lb, roff;
    if (bid < 1280)      { lev = 0; lb = bid;        roff = 0; }
    else if (bid < 1600) { lev = 1; lb = bid - 1280; roff = 262144; }
    else if (bid < 1680) { lev = 2; lb = bid - 1600; roff = 327680; }
    else if (bid < 1700) { lev = 3; lb = bid - 1680; roff = 344064; }
    else                 { lev = 4; lb = bid - 1700; roff = 348160; }
    const int start = lb * 4;                 // 4 units of 1024 float4, exact

    const f32x4* __restrict__ cls4 = (const f32x4*)P.cls[lev];
    const float* __restrict__ pss_l = P.pss[lev];
    unsigned short* __restrict__ mh_l = mh + (size_t)roff * 10;   // 10 chunks/row
    const int t = (int)threadIdx.x;
    const bool even = (t & 1) == 0;

    const f32x4* pc = cls4 + start * 1024 + t;
    f32x4 c0 = __builtin_nontemporal_load(pc);
    f32x4 c1 = __builtin_nontemporal_load(pc + 256);
    f32x4 c2 = __builtin_nontemporal_load(pc + 512);
    f32x4 c3 = __builtin_nontemporal_load(pc + 768);

    int u = start;
#pragma unroll
    for (int it = 0; it < 4; ++it) {
        const bool more = (it < 3);
        const f32x4* pn = cls4 + (more ? (u + 1) : u) * 1024 + t;
        f32x4 n0 = __builtin_nontemporal_load(pn);
        f32x4 n1 = __builtin_nontemporal_load(pn + 256);
        f32x4 n2 = __builtin_nontemporal_load(pn + 512);
        f32x4 n3 = __builtin_nontemporal_load(pn + 768);

        const int i4b = u * 1024 + t;
#pragma unroll
        for (int s = 0; s < 4; ++s) {
            f32x4 c = (s == 0) ? c0 : (s == 1) ? c1 : (s == 2) ? c2 : c3;
            int i4 = i4b + s * 256;
            float m = max4v(c);
            float m2 = fmaxf(m, __shfl_xor(m, 1));
            if (even) {
                int chunk = i4 >> 1;
                mh_l[chunk] = (unsigned short)(__float_as_uint(m2) >> 16);  // bf16 trunc
                float p = pss_l[chunk / 10];
                float E = __expf(-m2);
                float A = 1.0f + __expf(-p);
                float sc = __frcp_rn((1.0f + E) * A);
                if (sc >= FLOORV) {
                    int b = (int)((sc - FLOORV) * INV_BIN_W);
                    if (b > NBINS - 1) b = NBINS - 1;
                    atomicAdd(&lh[b], 1u);
                }
            }
        }
        u = u + 1; c0 = n0; c1 = n1; c2 = n2; c3 = n3;
    }

    __syncthreads();
    unsigned* h = histR + (size_t)(bid & (NREP - 1)) * (NUM_LEVELS * NBINS) + lev * NBINS;
    for (int i = threadIdx.x; i < NBINS; i += 256) {
        unsigned v = lh[i];
        if (v) atomicAdd(&h[i], v);
    }
}

// Coalesced replica reduction: 40 blocks (lev = bid/8, 256-bin segment each).
__global__ __launch_bounds__(256) void k_cutsum(const unsigned* histR, unsigned* hsum) {
    const int lev = blockIdx.x >> 3;
    const int seg = blockIdx.x & 7;
    const int b = seg * 256 + (int)threadIdx.x;
    unsigned s = 0;
#pragma unroll
    for (int rp = 0; rp < NREP; ++rp)
        s += histR[(size_t)rp * (NUM_LEVELS * NBINS) + lev * NBINS + b];
    hsum[lev * NBINS + b] = s;
}

// Scan summed hist for crossing; one margin bin; zero count.
__global__ __launch_bounds__(256) void k_cutpick(const unsigned* hsum, float* cutL, int* count) {
    __shared__ unsigned sh[NBINS];
    __shared__ unsigned ps[256];
    const int lev = blockIdx.x;
    const int t = (int)threadIdx.x;
    for (int i = t; i < NBINS; i += 256) sh[i] = hsum[lev * NBINS + i];   // coalesced
    __syncthreads();
    unsigned seg = 0;
#pragma unroll
    for (int j = 0; j < 8; ++j) seg += sh[t * 8 + j];
    ps[t] = seg;
    __syncthreads();
    if (t == 0) {
        long cum = 0;
        int sgi = 255;
        for (; sgi >= 0; --sgi) {
            if (cum + ps[sgi] >= TOPK) break;
            cum += ps[sgi];
        }
        int b = 0;
        if (sgi >= 0) {
            for (int j = sgi * 8 + 7; j >= sgi * 8; --j) {
                cum += sh[j];
                if (cum >= TOPK) { b = j; break; }
            }
        }
        int sel = (b <= 0) ? 0 : (b - 1);   // one margin bin below crossing
        cutL[lev] = FLOORV + (float)sel * BIN_W;
        count[lev] = 0;
    }
}

// Scan mh (7MB ushort, coalesced) vs per-row c-space cutoff; widened chunk margin
// (0.05) covers bf16 truncation; element test unchanged (exact f32 vs ct).
__global__ __launch_bounds__(1024) void k_compact(LevelParams P, const float* cutL,
                                                  const unsigned short* mh, int* count, int* cand) {
    const int bid = blockIdx.x;
    int lev, bstart, roff;
    if (bid < 2560)      { lev = 0; bstart = 0;    roff = 0; }
    else if (bid < 3200) { lev = 1; bstart = 2560; roff = 262144; }
    else if (bid < 3360) { lev = 2; bstart = 3200; roff = 327680; }
    else if (bid < 3400) { lev = 3; bstart = 3360; roff = 344064; }
    else                 { lev = 4; bstart = 3400; roff = 348160; }

    const int cid = (bid - bstart) * 1024 + (int)threadIdx.x;   // level-local chunk
    const float* __restrict__ pss_l = P.pss[lev];
    float mv = __uint_as_float((unsigned)mh[(size_t)roff * 10 + cid] << 16);
    float p = pss_l[cid / 10];
    float A = 1.0f + __expf(-p);
    const float thr = cutL[lev] - 1e-4f;
    float gg = __frcp_rn(thr * A) - 1.0f;            // e^-c <= gg <=> s >= thr
    float ct = (gg > 0.0f) ? (-__logf(gg) - 1e-2f) : 1e30f;
    bool pass = mv >= ct - 0.05f;                    // bf16-trunc slack
    if (__syncthreads_count(pass) == 0) return;

    __shared__ int lcount;
    __shared__ int lbase;
    __shared__ int lbuf[2048];
    if (threadIdx.x == 0) lcount = 0;
    __syncthreads();

    if (pass) {
        const float* __restrict__ cls = P.cls[lev];
        const int el = cid * 8;
        float4 c0 = *(const float4*)(cls + el);
        float4 c1 = *(const float4*)(cls + el + 4);
        float cs[8] = {c0.x, c0.y, c0.z, c0.w, c1.x, c1.y, c1.z, c1.w};
#pragma unroll
        for (int j = 0; j < 8; ++j) {
            if (cs[j] >= ct) {
                int li = atomicAdd(&lcount, 1);
                if (li < 2048) lbuf[li] = el + j;
            }
        }
    }
    __syncthreads();
    if (threadIdx.x == 0) lbase = atomicAdd(&count[lev], lcount);  // ONE global atomic/block
    __syncthreads();
    const int m = lcount < 2048 ? lcount : 2048;
    const int base = lbase;
    for (int i = threadIdx.x; i < m; i += 1024) {
        int pos = base + i;
        if (pos < CAND_CAP) cand[lev * CAND_CAP + pos] = lbuf[i];
    }
}

__global__ __launch_bounds__(1024) void k_final(LevelParams P, const int* cand, const int* count,
                                                const int* wptr, const int* hptr, float* out) {
    // Packed u64 keys: (f32 score bits << 32) | (0xFFFFFFFF - idx).
    // Descending u64 sort == descending score, ties -> ascending index.
    __shared__ unsigned long long sk[CAND_CAP];
    const int lev = blockIdx.x;
    int n = count[lev];
    if (n > CAND_CAP) n = CAND_CAP;
    int size = 1024;
    while (size < n) size <<= 1;  // 1024 / 2048 / 4096

    const float* __restrict__ cls = P.cls[lev];
    const float* __restrict__ pss = P.pss[lev];
    const float* __restrict__ box = P.box[lev];

    for (int i = threadIdx.x; i < size; i += 1024) {
        if (i < n) {
            int idx = cand[lev * CAND_CAP + i];
            float a32 = np_sigmoid_f32(cls[idx]);
            float b32 = np_sigmoid_f32(pss[idx / NUM_CLASSES]);
            float s = __fmul_rn(a32, b32);
            sk[i] = ((unsigned long long)(unsigned)__float_as_int(s) << 32)
                    | (unsigned long long)(0xFFFFFFFFu - (unsigned)idx);
        } else {
            sk[i] = 0ull;
        }
    }
    __syncthreads();

    for (int k = 2; k <= size; k <<= 1) {
        for (int j = k >> 1; j > 0; j >>= 1) {
            for (int t = threadIdx.x; t < (size >> 1); t += 1024) {
                int i = ((t & ~(j - 1)) << 1) | (t & (j - 1));
                int ix = i | j;
                unsigned long long a = sk[i], b = sk[ix];
                bool dirDesc = ((i & k) == 0);
                if ((a > b) != dirDesc) {
                    sk[i] = b; sk[ix] = a;
                }
            }
            __syncthreads();
        }
    }

    const float w = (float)wptr[0], h = (float)hptr[0];
    const float invw = 1.0f / w, invh = 1.0f / h;
    for (int r = threadIdx.x; r < TOPK; r += 1024) {
        unsigned long long v = sk[r];
        float s = __int_as_float((int)(unsigned)(v >> 32));
        int idx = (int)(0xFFFFFFFFu - (unsigned)(v & 0xFFFFFFFFull));
        bool keep = (r < n) && (s > 0.05f);
        int row = lev * TOPK + r;
        float b0 = 0.f, b1 = 0.f, b2 = 0.f, b3 = 0.f;
        if (keep) {
            int a = idx / NUM_CLASSES;
            b0 = fminf(fmaxf(box[a * 4 + 0] * invw, 0.f), 1.f);
            b1 = fminf(fmaxf(box[a * 4 + 1] * invh, 0.f), 1.f);
            b2 = fminf(fmaxf(box[a * 4 + 2] * invw, 0.f), 1.f);
            b3 = fminf(fmaxf(box[a * 4 + 3] * invh, 0.f), 1.f);
        }
        out[row * 4 + 0] = b0;
        out[row * 4 + 1] = b1;
        out[row * 4 + 2] = b2;
        out[row * 4 + 3] = b3;
        out[NUM_LEVELS * TOPK * 4 + row] = keep ? s : 0.0f;
        out[NUM_LEVELS * TOPK * 5 + row] = keep ? (float)(idx % NUM_CLASSES) : -1.0f;
    }
}

extern "C" void kernel_launch(void* const* d_in, const int* in_sizes, int n_in,
                              void* d_out, int out_size, void* d_ws, size_t ws_size,
                              hipStream_t stream) {
    LevelParams P;
    for (int i = 0; i < NUM_LEVELS; ++i) {
        P.cls[i] = (const float*)d_in[3 * i + 0];
        P.box[i] = (const float*)d_in[3 * i + 1];
        P.pss[i] = (const float*)d_in[3 * i + 2];
    }
    const int* wp = (const int*)d_in[15];
    const int* hp = (const int*)d_in[16];

    unsigned char* ws = (unsigned char*)d_ws;
    unsigned* histR = (unsigned*)ws;                 // 16*5*2048*4 = 655,360
    float* cutL = (float*)(ws + 655360);             // 20 B
    int* count = (int*)(ws + 655380);                // 20 B
    unsigned* hsum = (unsigned*)(ws + 655424);       // 5*2048*4 = 40,960 -> ends 696,384
    unsigned short* mh = (unsigned short*)(ws + 696384);  // 3,491,840*2 -> ends 7,680,064
    int* cand = (int*)(ws + 7680064);                // 81,920

    k_zero<<<640, 256, 0, stream>>>(histR);
    k_hist<<<1705, 256, 0, stream>>>(P, histR, mh);
    k_cutsum<<<40, 256, 0, stream>>>(histR, hsum);
    k_cutpick<<<NUM_LEVELS, 256, 0, stream>>>(hsum, cutL, count);
    k_compact<<<3410, 1024, 0, stream>>>(P, cutL, mh, count, cand);
    k_final<<<NUM_LEVELS, 1024, 0, stream>>>(P, cand, count, wp, hp, (float*)d_out);
}

// Round 23
// 92.346 us; speedup vs baseline: 1.1082x; 1.0141x over previous
//
#include <hip/hip_runtime.h>
#include <math.h>

#define NUM_LEVELS 5
#define NUM_CLASSES 80
#define TOPK 1000
#define CAND_CAP 4096
#define NBINS 2048
#define NREP 16
#define FLOORV 0.5f
#define BIN_W (0.5f / 2048.0f)
#define INV_BIN_W (2048.0f / 0.5f)
#define ROW_EPS (-1e-3f)   // sig(-1e-3)=0.49975 < thr_min-1e-4: filtered rows can't qualify

typedef float f32x4 __attribute__((ext_vector_type(4)));

struct LevelParams {
    const float* cls[NUM_LEVELS];
    const float* box[NUM_LEVELS];
    const float* pss[NUM_LEVELS];
};

// Step-rounded f32 sigmoid, numpy scalar semantics (bit-matches golden; R6-R22 pass).
__device__ __forceinline__ float np_sigmoid_f32(float x) {
    float e32 = (float)exp(-(double)x);
    float d = __fadd_rn(1.0f, e32);
    return __fdiv_rn(1.0f, d);
}

__device__ __forceinline__ float max8v(f32x4 a, f32x4 b) {
    return fmaxf(fmaxf(fmaxf(a.x, a.y), fmaxf(a.z, a.w)),
                 fmaxf(fmaxf(b.x, b.y), fmaxf(b.z, b.w)));
}

// Zero histR (16*5*2048 u32).
__global__ __launch_bounds__(256) void k_zero(unsigned* histR) {
    histR[blockIdx.x * 256 + threadIdx.x] = 0u;   // 640*256 == 163840 exact
}

// Row-filtered stream: thread <-> 16 consecutive elems (one 64B line, one row).
// Rows with p <= -1e-3 can never reach the 0.5 floor -> skip their cls lines
// entirely (~50% DRAM traffic saved). mh=0 for inactive chunks (k_compact
// re-derives inactivity from pss independently, so the value is never used).
__global__ __launch_bounds__(256) void k_hist(LevelParams P, unsigned* histR, unsigned short* mh) {
    __shared__ unsigned lh[NBINS];
    for (int i = threadIdx.x; i < NBINS; i += 256) lh[i] = 0;
    __syncthreads();

    const int bid = blockIdx.x;
    int lev, lb, roff;
    if (bid < 1280)      { lev = 0; lb = bid;        roff = 0; }
    else if (bid < 1600) { lev = 1; lb = bid - 1280; roff = 262144; }
    else if (bid < 1680) { lev = 2; lb = bid - 1600; roff = 327680; }
    else if (bid < 1700) { lev = 3; lb = bid - 1680; roff = 344064; }
    else                 { lev = 4; lb = bid - 1700; roff = 348160; }
    const int start = lb * 4;                 // 4 units of 256 slots (16 elems each)

    const f32x4* __restrict__ cls4 = (const f32x4*)P.cls[lev];
    const float* __restrict__ pss_l = P.pss[lev];
    unsigned short* __restrict__ mh_l = mh + (size_t)roff * 10;   // 10 chunks/row
    const int t = (int)threadIdx.x;

    // prologue: slot 0 state
    int slot = start * 256 + t;
    float pv = pss_l[slot / 5];               // 16-elem slot sits in one row (80=5*16)
    bool act = pv > ROW_EPS;
    f32x4 c0 = {}, c1 = {}, c2 = {}, c3 = {};
    if (act) {
        const f32x4* pc = cls4 + slot * 4;
        c0 = __builtin_nontemporal_load(pc);
        c1 = __builtin_nontemporal_load(pc + 1);
        c2 = __builtin_nontemporal_load(pc + 2);
        c3 = __builtin_nontemporal_load(pc + 3);
    }

#pragma unroll
    for (int it = 0; it < 4; ++it) {
        // prefetch next slot (2-deep pipeline)
        int slot2 = (it < 3) ? slot + 256 : slot;
        float pv2 = pss_l[slot2 / 5];
        bool act2 = pv2 > ROW_EPS;
        f32x4 n0 = {}, n1 = {}, n2 = {}, n3 = {};
        if (act2 && it < 3) {
            const f32x4* pn = cls4 + slot2 * 4;
            n0 = __builtin_nontemporal_load(pn);
            n1 = __builtin_nontemporal_load(pn + 1);
            n2 = __builtin_nontemporal_load(pn + 2);
            n3 = __builtin_nontemporal_load(pn + 3);
        }

        // process current slot
        unsigned short usa = 0, usb = 0;
        if (act) {
            float m8a = max8v(c0, c1);
            float m8b = max8v(c2, c3);
            usa = (unsigned short)(__float_as_uint(m8a) >> 16);   // bf16 trunc
            usb = (unsigned short)(__float_as_uint(m8b) >> 16);
            float A = 1.0f + __expf(-pv);
            float Ea = __expf(-m8a);
            float sca = __frcp_rn((1.0f + Ea) * A);
            if (sca >= FLOORV) {
                int b = (int)((sca - FLOORV) * INV_BIN_W);
                if (b > NBINS - 1) b = NBINS - 1;
                atomicAdd(&lh[b], 1u);
            }
            float Eb = __expf(-m8b);
            float scb = __frcp_rn((1.0f + Eb) * A);
            if (scb >= FLOORV) {
                int b = (int)((scb - FLOORV) * INV_BIN_W);
                if (b > NBINS - 1) b = NBINS - 1;
                atomicAdd(&lh[b], 1u);
            }
        }
        // chunk pair (2*slot, 2*slot+1): 4B coalesced store
        unsigned short us2[2] = {usa, usb};
        *(unsigned*)(mh_l + (size_t)slot * 2) = *(unsigned*)us2;

        slot = slot2; pv = pv2; act = act2;
        c0 = n0; c1 = n1; c2 = n2; c3 = n3;
    }

    __syncthreads();
    unsigned* h = histR + (size_t)(bid & (NREP - 1)) * (NUM_LEVELS * NBINS) + lev * NBINS;
    for (int i = threadIdx.x; i < NBINS; i += 256) {
        unsigned v = lh[i];
        if (v) atomicAdd(&h[i], v);
    }
}

// Coalesced replica reduction: 40 blocks (lev = bid/8, 256-bin segment each).
__global__ __launch_bounds__(256) void k_cutsum(const unsigned* histR, unsigned* hsum) {
    const int lev = blockIdx.x >> 3;
    const int seg = blockIdx.x & 7;
    const int b = seg * 256 + (int)threadIdx.x;
    unsigned s = 0;
#pragma unroll
    for (int rp = 0; rp < NREP; ++rp)
        s += histR[(size_t)rp * (NUM_LEVELS * NBINS) + lev * NBINS + b];
    hsum[lev * NBINS + b] = s;
}

// Scan summed hist for crossing; one margin bin; zero count.
__global__ __launch_bounds__(256) void k_cutpick(const unsigned* hsum, float* cutL, int* count) {
    __shared__ unsigned sh[NBINS];
    __shared__ unsigned ps[256];
    const int lev = blockIdx.x;
    const int t = (int)threadIdx.x;
    for (int i = t; i < NBINS; i += 256) sh[i] = hsum[lev * NBINS + i];   // coalesced
    __syncthreads();
    unsigned seg = 0;
#pragma unroll
    for (int j = 0; j < 8; ++j) seg += sh[t * 8 + j];
    ps[t] = seg;
    __syncthreads();
    if (t == 0) {
        long cum = 0;
        int sgi = 255;
        for (; sgi >= 0; --sgi) {
            if (cum + ps[sgi] >= TOPK) break;
            cum += ps[sgi];
        }
        int b = 0;
        if (sgi >= 0) {
            for (int j = sgi * 8 + 7; j >= sgi * 8; --j) {
                cum += sh[j];
                if (cum >= TOPK) { b = j; break; }
            }
        }
        int sel = (b <= 0) ? 0 : (b - 1);   // one margin bin below crossing
        cutL[lev] = FLOORV + (float)sel * BIN_W;
        count[lev] = 0;
    }
}

// Scan mh (7MB ushort, coalesced) vs per-row c-space cutoff; bf16-trunc slack on
// chunk skip; element test exact f32 vs ct. Byte-identical to R22 (passed).
__global__ __launch_bounds__(1024) void k_compact(LevelParams P, const float* cutL,
                                                  const unsigned short* mh, int* count, int* cand) {
    const int bid = blockIdx.x;
    int lev, bstart, roff;
    if (bid < 2560)      { lev = 0; bstart = 0;    roff = 0; }
    else if (bid < 3200) { lev = 1; bstart = 2560; roff = 262144; }
    else if (bid < 3360) { lev = 2; bstart = 3200; roff = 327680; }
    else if (bid < 3400) { lev = 3; bstart = 3360; roff = 344064; }
    else                 { lev = 4; bstart = 3400; roff = 348160; }

    const int cid = (bid - bstart) * 1024 + (int)threadIdx.x;   // level-local chunk
    const float* __restrict__ pss_l = P.pss[lev];
    float mv = __uint_as_float((unsigned)mh[(size_t)roff * 10 + cid] << 16);
    float p = pss_l[cid / 10];
    float A = 1.0f + __expf(-p);
    const float thr = cutL[lev] - 1e-4f;
    float gg = __frcp_rn(thr * A) - 1.0f;            // e^-c <= gg <=> s >= thr
    float ct = (gg > 0.0f) ? (-__logf(gg) - 1e-2f) : 1e30f;
    bool pass = mv >= ct - 0.05f;                    // bf16-trunc slack
    if (__syncthreads_count(pass) == 0) return;

    __shared__ int lcount;
    __shared__ int lbase;
    __shared__ int lbuf[2048];
    if (threadIdx.x == 0) lcount = 0;
    __syncthreads();

    if (pass) {
        const float* __restrict__ cls = P.cls[lev];
        const int el = cid * 8;
        float4 c0 = *(const float4*)(cls + el);
        float4 c1 = *(const float4*)(cls + el + 4);
        float cs[8] = {c0.x, c0.y, c0.z, c0.w, c1.x, c1.y, c1.z, c1.w};
#pragma unroll
        for (int j = 0; j < 8; ++j) {
            if (cs[j] >= ct) {
                int li = atomicAdd(&lcount, 1);
                if (li < 2048) lbuf[li] = el + j;
            }
        }
    }
    __syncthreads();
    if (threadIdx.x == 0) lbase = atomicAdd(&count[lev], lcount);  // ONE global atomic/block
    __syncthreads();
    const int m = lcount < 2048 ? lcount : 2048;
    const int base = lbase;
    for (int i = threadIdx.x; i < m; i += 1024) {
        int pos = base + i;
        if (pos < CAND_CAP) cand[lev * CAND_CAP + pos] = lbuf[i];
    }
}

__global__ __launch_bounds__(1024) void k_final(LevelParams P, const int* cand, const int* count,
                                                const int* wptr, const int* hptr, float* out) {
    // Packed u64 keys: (f32 score bits << 32) | (0xFFFFFFFF - idx).
    // Descending u64 sort == descending score, ties -> ascending index.
    __shared__ unsigned long long sk[CAND_CAP];
    const int lev = blockIdx.x;
    int n = count[lev];
    if (n > CAND_CAP) n = CAND_CAP;
    int size = 1024;
    while (size < n) size <<= 1;  // 1024 / 2048 / 4096

    const float* __restrict__ cls = P.cls[lev];
    const float* __restrict__ pss = P.pss[lev];
    const float* __restrict__ box = P.box[lev];

    for (int i = threadIdx.x; i < size; i += 1024) {
        if (i < n) {
            int idx = cand[lev * CAND_CAP + i];
            float a32 = np_sigmoid_f32(cls[idx]);
            float b32 = np_sigmoid_f32(pss[idx / NUM_CLASSES]);
            float s = __fmul_rn(a32, b32);
            sk[i] = ((unsigned long long)(unsigned)__float_as_int(s) << 32)
                    | (unsigned long long)(0xFFFFFFFFu - (unsigned)idx);
        } else {
            sk[i] = 0ull;
        }
    }
    __syncthreads();

    for (int k = 2; k <= size; k <<= 1) {
        for (int j = k >> 1; j > 0; j >>= 1) {
            for (int t = threadIdx.x; t < (size >> 1); t += 1024) {
                int i = ((t & ~(j - 1)) << 1) | (t & (j - 1));
                int ix = i | j;
                unsigned long long a = sk[i], b = sk[ix];
                bool dirDesc = ((i & k) == 0);
                if ((a > b) != dirDesc) {
                    sk[i] = b; sk[ix] = a;
                }
            }
            __syncthreads();
        }
    }

    const float w = (float)wptr[0], h = (float)hptr[0];
    const float invw = 1.0f / w, invh = 1.0f / h;
    for (int r = threadIdx.x; r < TOPK; r += 1024) {
        unsigned long long v = sk[r];
        float s = __int_as_float((int)(unsigned)(v >> 32));
        int idx = (int)(0xFFFFFFFFu - (unsigned)(v & 0xFFFFFFFFull));
        bool keep = (r < n) && (s > 0.05f);
        int row = lev * TOPK + r;
        float b0 = 0.f, b1 = 0.f, b2 = 0.f, b3 = 0.f;
        if (keep) {
            int a = idx / NUM_CLASSES;
            b0 = fminf(fmaxf(box[a * 4 + 0] * invw, 0.f), 1.f);
            b1 = fminf(fmaxf(box[a * 4 + 1] * invh, 0.f), 1.f);
            b2 = fminf(fmaxf(box[a * 4 + 2] * invw, 0.f), 1.f);
            b3 = fminf(fmaxf(box[a * 4 + 3] * invh, 0.f), 1.f);
        }
        out[row * 4 + 0] = b0;
        out[row * 4 + 1] = b1;
        out[row * 4 + 2] = b2;
        out[row * 4 + 3] = b3;
        out[NUM_LEVELS * TOPK * 4 + row] = keep ? s : 0.0f;
        out[NUM_LEVELS * TOPK * 5 + row] = keep ? (float)(idx % NUM_CLASSES) : -1.0f;
    }
}

extern "C" void kernel_launch(void* const* d_in, const int* in_sizes, int n_in,
                              void* d_out, int out_size, void* d_ws, size_t ws_size,
                              hipStream_t stream) {
    LevelParams P;
    for (int i = 0; i < NUM_LEVELS; ++i) {
        P.cls[i] = (const float*)d_in[3 * i + 0];
        P.box[i] = (const float*)d_in[3 * i + 1];
        P.pss[i] = (const float*)d_in[3 * i + 2];
    }
    const int* wp = (const int*)d_in[15];
    const int* hp = (const int*)d_in[16];

    unsigned char* ws = (unsigned char*)d_ws;
    unsigned* histR = (unsigned*)ws;                 // 16*5*2048*4 = 655,360
    float* cutL = (float*)(ws + 655360);             // 20 B
    int* count = (int*)(ws + 655380);                // 20 B
    unsigned* hsum = (unsigned*)(ws + 655424);       // 5*2048*4 = 40,960 -> ends 696,384
    unsigned short* mh = (unsigned short*)(ws + 696384);  // 3,491,840*2 -> ends 7,680,064
    int* cand = (int*)(ws + 7680064);                // 81,920

    k_zero<<<640, 256, 0, stream>>>(histR);
    k_hist<<<1705, 256, 0, stream>>>(P, histR, mh);
    k_cutsum<<<40, 256, 0, stream>>>(histR, hsum);
    k_cutpick<<<NUM_LEVELS, 256, 0, stream>>>(hsum, cutL, count);
    k_compact<<<3410, 1024, 0, stream>>>(P, cutL, mh, count, cand);
    k_final<<<NUM_LEVELS, 1024, 0, stream>>>(P, cand, count, wp, hp, (float*)d_out);
}